// Round 11
// baseline (233.303 us; speedup 1.0000x reference)
//
#include <hip/hip_runtime.h>
#include <hip/hip_bf16.h>

#define N_ 32
#define CIN_ 64
#define COUT_ 64
#define T_ 64
#define V_ 128
#define K_ 128  // RED_*T_

#define C2LOG2E 2.88539008177792681f  // 2*log2(e): tanh(x)=1-2/(2^(C*x)+1)

typedef __attribute__((ext_vector_type(8))) short short8v;  // 8 bf16 = 4 VGPR
typedef __attribute__((ext_vector_type(4))) short short4v;  // 4 bf16 = 2 VGPR
typedef __attribute__((ext_vector_type(4))) float f32x4;    // MFMA acc

// d = 2*log2e*(b-a) pre-scaled in k1 -> tanh = 1 - 2/(exp2(d)+1)
__device__ __forceinline__ float tanh_ps(float d) {
    float e = __builtin_amdgcn_exp2f(d);
    return 1.0f - 2.0f * __builtin_amdgcn_rcpf(e + 1.0f);
}
__device__ __forceinline__ unsigned short f2bf(float f) {
    __hip_bfloat16 h = __float2bfloat16(f);
    return *reinterpret_cast<unsigned short*>(&h);
}

// fragment k-order: element jj of chunk (kc,g) holds k = kc*32 + 4g + (jj<4 ? jj : 12+jj)
// flat fragment index k' = (kc*4+g)*8 + jj
__device__ __forceinline__ int kprime(int k) {
    int kc = k >> 5, kk = k & 31;
    int hi = kk >> 4;
    int base = kk & 15;
    int g = base >> 2, j = base & 3;
    return kc * 32 + g * 8 + hi * 4 + j;
}

// a_pack float index: lane-contiguous (8 floats) AND wave-contiguous (2KB/frag)
__device__ __forceinline__ size_t apos(int n, int v, int kp) {
    return (size_t)n * 16384 + (size_t)(v >> 4) * 2048
         + (size_t)(kp >> 3) * 128 + (size_t)(v & 15) * 8 + (kp & 7);
}

// ---------------------------------------------------------------------------
// k0a: AT[o][w][v] = A[o][v][w]  (4 MB, tiled 32x32 LDS transpose)
// ---------------------------------------------------------------------------
__global__ __launch_bounds__(256) void k0_transpose_A(
    const float* __restrict__ A, float* __restrict__ AT)
{
    __shared__ float t[32][33];
    const int o  = blockIdx.x;
    const int v0 = (blockIdx.y >> 2) * 32, w0 = (blockIdx.y & 3) * 32;
    const float* Ao = A  + (size_t)o * (V_ * V_);
    float*      ATo = AT + (size_t)o * (V_ * V_);
    for (int i = threadIdx.x; i < 1024; i += 256) {
        int r = i >> 5, c = i & 31;
        t[r][c] = Ao[(v0 + r) * V_ + (w0 + c)];
    }
    __syncthreads();
    for (int i = threadIdx.x; i < 1024; i += 256) {
        int r = i >> 5, c = i & 31;
        ATo[(w0 + r) * V_ + (v0 + c)] = t[c][r];
    }
}

// ---------------------------------------------------------------------------
// k0bc: fused weight-fragment prep (Wrm table 16 KB; {Wf|Wm1,Wm2} table 10 KB)
// ---------------------------------------------------------------------------
__global__ __launch_bounds__(256) void k0bc_frag(
    const float* __restrict__ Wrm, const float* __restrict__ Wf,
    const float* __restrict__ Wm1, const float* __restrict__ Wm2,
    unsigned short* __restrict__ wfrag, unsigned short* __restrict__ wffrag)
{
    const int flat = blockIdx.x * 256 + threadIdx.x;
    if (flat < 1024) {
        const int ent = flat;
        const int lane = ent & 63, kc = (ent >> 6) & 3, ot = ent >> 8;
        const int l15 = lane & 15, g = lane >> 4;
        const float* wr = Wrm + (size_t)(ot * 16 + l15) * K_ + kc * 32 + 4 * g;
        short8v f;
        #pragma unroll
        for (int j = 0; j < 4; ++j) f[j]     = (short)f2bf(wr[j]);
        #pragma unroll
        for (int j = 0; j < 4; ++j) f[4 + j] = (short)f2bf(wr[16 + j]);
        reinterpret_cast<short8v*>(wfrag)[ent] = f;
    } else if (flat < 1024 + 640) {
        const int ent = flat - 1024;
        const int lane = ent & 63, kc = (ent >> 6) & 1, ot = ent >> 7;
        const int l15 = lane & 15, g = lane >> 4;
        short8v f = (short8v){0, 0, 0, 0, 0, 0, 0, 0};
        const float* wr = nullptr;
        if (ot < 4)          wr = Wf  + (size_t)(ot * 16 + l15) * CIN_;
        else if (l15 < 2)    wr = Wm1 + (size_t)l15 * CIN_;
        else if (l15 < 4)    wr = Wm2 + (size_t)(l15 - 2) * CIN_;
        if (wr) {
            wr += kc * 32 + 4 * g;
            #pragma unroll
            for (int j = 0; j < 4; ++j) f[j]     = (short)f2bf(wr[j]);
            #pragma unroll
            for (int j = 0; j < 4; ++j) f[4 + j] = (short)f2bf(wr[16 + j]);
        }
        reinterpret_cast<short8v*>(wffrag)[ent] = f;
    }
}

// ---------------------------------------------------------------------------
// k1: all three 1x1 convs as one MFMA GEMM. Per block (n, 256-col tv chunk).
// a_pack/bT PRE-SCALED by 2*log2e (both feed only k2's tanh argument).
// ---------------------------------------------------------------------------
__global__ __launch_bounds__(256) void k1_mfma(
    const float* __restrict__ x,
    const unsigned short* __restrict__ wffrag,
    const float* __restrict__ bfv,
    const float* __restrict__ bm1, const float* __restrict__ bm2,
    unsigned short* __restrict__ xf, float* __restrict__ a_pack,
    float* __restrict__ bT)
{
    const int n = blockIdx.x, tv0 = blockIdx.y * 256;
    const int tid = threadIdx.x, lane = tid & 63, wid = tid >> 6;
    const int l15 = lane & 15, g = lane >> 4;
    const float* xn = x + (size_t)n * (CIN_ * T_ * V_);
    const int colbase = tv0 + wid * 64 + l15;

    f32x4 acc[5][4];
    #pragma unroll
    for (int ot = 0; ot < 5; ++ot)
        #pragma unroll
        for (int nt = 0; nt < 4; ++nt)
            acc[ot][nt] = (f32x4){0.f, 0.f, 0.f, 0.f};

    const short8v* wf = reinterpret_cast<const short8v*>(wffrag);
    #pragma unroll
    for (int kc = 0; kc < 2; ++kc) {
        short8v bfrag[4];
        #pragma unroll
        for (int nt = 0; nt < 4; ++nt) {
            const float* xp = xn + (size_t)(kc * 32 + 4 * g) * (T_ * V_)
                            + colbase + nt * 16;
            short8v t;
            #pragma unroll
            for (int j = 0; j < 4; ++j)
                t[j]     = (short)f2bf(xp[(size_t)j * (T_ * V_)]);
            #pragma unroll
            for (int j = 0; j < 4; ++j)
                t[4 + j] = (short)f2bf(xp[(size_t)(16 + j) * (T_ * V_)]);
            bfrag[nt] = t;
        }
        #pragma unroll
        for (int ot = 0; ot < 5; ++ot) {
            short8v wv = wf[(ot * 2 + kc) * 64 + lane];
            #pragma unroll
            for (int nt = 0; nt < 4; ++nt)
                acc[ot][nt] = __builtin_amdgcn_mfma_f32_16x16x32_bf16(
                    wv, bfrag[nt], acc[ot][nt], 0, 0, 0);
        }
    }

    // xf epilogue: row o = ot*16+4g+r, col = colbase+nt*16
    #pragma unroll
    for (int ot = 0; ot < 4; ++ot) {
        float4 bias = *reinterpret_cast<const float4*>(bfv + ot * 16 + 4 * g);
        const float bi[4] = {bias.x, bias.y, bias.z, bias.w};
        #pragma unroll
        for (int nt = 0; nt < 4; ++nt) {
            const int col = colbase + nt * 16;
            #pragma unroll
            for (int r = 0; r < 4; ++r) {
                const int o = ot * 16 + 4 * g + r;
                xf[((size_t)n * COUT_ + o) * (T_ * V_) + col] =
                    f2bf(acc[ot][nt][r] + bi[r]);
            }
        }
    }

    // a/b epilogue: only g==0 lanes hold rows 0..3 of the Wm tile
    if (g == 0) {
        const float b10 = bm1[0], b11 = bm1[1], b20 = bm2[0], b21 = bm2[1];
        #pragma unroll
        for (int nt = 0; nt < 4; ++nt) {
            const int tv = colbase + nt * 16;
            const int t = tv >> 7, v = tv & 127;
            a_pack[apos(n, v, kprime(t))]      = C2LOG2E * (acc[4][nt][0] + b10);
            a_pack[apos(n, v, kprime(64 + t))] = C2LOG2E * (acc[4][nt][1] + b11);
            float* btp = bT + ((size_t)n * V_ + v) * K_;
            btp[t]      = C2LOG2E * (acc[4][nt][2] + b20);
            btp[64 + t] = C2LOG2E * (acc[4][nt][3] + b21);
        }
    }
}

// ---------------------------------------------------------------------------
// k2: MFMA. Per block (n, w, v-half): C'[64 o][64 v] = sum_k Wrm[o][k]*tanh(...)
// R11: v-SPLIT (not o-split: every tanh still computed exactly once).
// Halves live registers: e[4] (16 VGPR) + acc[4] (16 acc) vs R10's 32+32 —
// R9/R10 showed occupancy was register-capped (~4 waves/SIMD), not LDS-capped.
// Single-pass epilogue (R10's 2-pass serialization regressed).
// ---------------------------------------------------------------------------
__global__ __launch_bounds__(256) void k2_mfma(
    const float* __restrict__ a_pack, const float* __restrict__ bT,
    const unsigned short* __restrict__ wfrag, const float* __restrict__ brm,
    const float* __restrict__ AT, unsigned short* __restrict__ xmT)
{
    __shared__ float tile[COUT_][66];  // [o][vlocal], 16.9 KB, stride 66
    const int n = blockIdx.x;
    const int w = blockIdx.y >> 1, vh = blockIdx.y & 1;
    const int tid  = threadIdx.x;
    const int lane = tid & 63, wid = tid >> 6;
    const int l15  = lane & 15, g = lane >> 4;

    const float* bt = bT + ((size_t)n * V_ + w) * K_;
    // v = vh*64 + wid*16 + l15 ; v>>4 = vh*4+wid, v&15 = l15
    const float* ap = a_pack + (size_t)n * 16384
                    + (size_t)(vh * 4 + wid) * 2048 + (size_t)l15 * 8;

    short8v e[4];
    #pragma unroll
    for (int kc = 0; kc < 4; ++kc) {
        float4 a0 = *reinterpret_cast<const float4*>(ap + (kc * 4 + g) * 128);
        float4 a1 = *reinterpret_cast<const float4*>(ap + (kc * 4 + g) * 128 + 4);
        float4 bl = *reinterpret_cast<const float4*>(bt + kc * 32 + 4 * g);
        float4 bh = *reinterpret_cast<const float4*>(bt + kc * 32 + 4 * g + 16);
        short8v t;
        t[0] = (short)f2bf(tanh_ps(bl.x - a0.x));
        t[1] = (short)f2bf(tanh_ps(bl.y - a0.y));
        t[2] = (short)f2bf(tanh_ps(bl.z - a0.z));
        t[3] = (short)f2bf(tanh_ps(bl.w - a0.w));
        t[4] = (short)f2bf(tanh_ps(bh.x - a1.x));
        t[5] = (short)f2bf(tanh_ps(bh.y - a1.y));
        t[6] = (short)f2bf(tanh_ps(bh.z - a1.z));
        t[7] = (short)f2bf(tanh_ps(bh.w - a1.w));
        e[kc] = t;
    }

    const short8v* wf = reinterpret_cast<const short8v*>(wfrag);
    f32x4 acc[4];
    #pragma unroll
    for (int ot = 0; ot < 4; ++ot)
        acc[ot] = (f32x4){0.f, 0.f, 0.f, 0.f};
    #pragma unroll
    for (int ot = 0; ot < 4; ++ot)
        #pragma unroll
        for (int kc = 0; kc < 4; ++kc) {
            short8v wv = wf[(ot * 4 + kc) * 64 + lane];
            acc[ot] = __builtin_amdgcn_mfma_f32_16x16x32_bf16(wv, e[kc], acc[ot], 0, 0, 0);
        }

    // acc -> tile: row o = ot*16+4g+r, col = wid*16+l15
    #pragma unroll
    for (int ot = 0; ot < 4; ++ot)
        #pragma unroll
        for (int r = 0; r < 4; ++r)
            tile[ot * 16 + 4 * g + r][wid * 16 + l15] = acc[ot][r];
    __syncthreads();

    // dump: xmT[n][o][w][vh*64 + 2vp..] = brm[o] + AT[o][w][v] - tile[o][vloc]
    for (int i = tid; i < COUT_ * 32; i += 256) {
        int o = i >> 5, vp = i & 31;  // vp = local v-pair (0..31)
        float2 tv2 = *reinterpret_cast<const float2*>(&tile[o][2 * vp]);
        float2 at = *reinterpret_cast<const float2*>(
            AT + ((size_t)o * V_ + w) * V_ + vh * 64 + 2 * vp);
        float br = brm[o];
        unsigned u = (unsigned)f2bf(br + at.x - tv2.x)
                   | ((unsigned)f2bf(br + at.y - tv2.y) << 16);
        reinterpret_cast<unsigned*>(xmT)[
            (((size_t)n * COUT_ + o) * V_ + w) * 64 + vh * 32 + vp] = u;
    }
}

// ---------------------------------------------------------------------------
// k3: MFMA. Per block (n, t): out[c][w] = sum_v xf[c][v] * xmT[t][w][v].
// ---------------------------------------------------------------------------
__global__ __launch_bounds__(256) void k3_mfma(
    const unsigned short* __restrict__ xf,
    const unsigned short* __restrict__ xmT,
    float* __restrict__ out)
{
    __shared__ unsigned short xfl[COUT_ * V_];
    __shared__ unsigned short xml[V_ * V_];
    const int n = blockIdx.x, t = blockIdx.y;
    const int tid  = threadIdx.x;
    const int lane = tid & 63, wid = tid >> 6;
    const int l15  = lane & 15, g = lane >> 4;

    for (int i = tid; i < 1024; i += 256) {
        int c = i >> 4, ch = i & 15;
        float4 d = *reinterpret_cast<const float4*>(
            xf + (((size_t)n * COUT_ + c) * T_ + t) * V_ + ch * 8);
        int dst = c * 256 + ((ch * 16) ^ ((c & 7) << 4));
        *reinterpret_cast<float4*>(reinterpret_cast<char*>(xfl) + dst) = d;
    }
    for (int i = tid; i < 2048; i += 256) {
        int wq = i >> 4, ch = i & 15;
        float4 d = *reinterpret_cast<const float4*>(
            xmT + (((size_t)n * COUT_ + t) * V_ + wq) * V_ + ch * 8);
        int dst = wq * 256 + ((ch * 16) ^ ((wq & 7) << 4));
        *reinterpret_cast<float4*>(reinterpret_cast<char*>(xml) + dst) = d;
    }
    __syncthreads();

    f32x4 acc[4][2];
    #pragma unroll
    for (int ct = 0; ct < 4; ++ct) {
        acc[ct][0] = (f32x4){0.f, 0.f, 0.f, 0.f};
        acc[ct][1] = (f32x4){0.f, 0.f, 0.f, 0.f};
    }

    #pragma unroll
    for (int kc = 0; kc < 4; ++kc) {
        const int vb0 = (kc * 32 + 4 * g) * 2;
        const int vb1 = vb0 + 32;
        short8v af[4];
        #pragma unroll
        for (int ct = 0; ct < 4; ++ct) {
            int c = ct * 16 + l15, sw = (c & 7) << 4;
            short4v lo = *reinterpret_cast<const short4v*>(
                reinterpret_cast<const char*>(xfl) + c * 256 + (vb0 ^ sw));
            short4v hi = *reinterpret_cast<const short4v*>(
                reinterpret_cast<const char*>(xfl) + c * 256 + (vb1 ^ sw));
            af[ct] = __builtin_shufflevector(lo, hi, 0, 1, 2, 3, 4, 5, 6, 7);
        }
        short8v bg[2];
        #pragma unroll
        for (int wt = 0; wt < 2; ++wt) {
            int wq = wid * 32 + wt * 16 + l15, sw = (wq & 7) << 4;
            short4v lo = *reinterpret_cast<const short4v*>(
                reinterpret_cast<const char*>(xml) + wq * 256 + (vb0 ^ sw));
            short4v hi = *reinterpret_cast<const short4v*>(
                reinterpret_cast<const char*>(xml) + wq * 256 + (vb1 ^ sw));
            bg[wt] = __builtin_shufflevector(lo, hi, 0, 1, 2, 3, 4, 5, 6, 7);
        }
        #pragma unroll
        for (int ct = 0; ct < 4; ++ct)
            #pragma unroll
            for (int wt = 0; wt < 2; ++wt)
                acc[ct][wt] = __builtin_amdgcn_mfma_f32_16x16x32_bf16(
                    af[ct], bg[wt], acc[ct][wt], 0, 0, 0);
    }

    #pragma unroll
    for (int ct = 0; ct < 4; ++ct)
        #pragma unroll
        for (int wt = 0; wt < 2; ++wt)
            #pragma unroll
            for (int r = 0; r < 4; ++r) {
                int c = ct * 16 + 4 * g + r;
                int wcol = wid * 32 + wt * 16 + l15;
                out[(((size_t)n * COUT_ + c) * T_ + t) * V_ + wcol] = acc[ct][wt][r];
            }
}

extern "C" void kernel_launch(void* const* d_in, const int* in_sizes, int n_in,
                              void* d_out, int out_size, void* d_ws, size_t ws_size,
                              hipStream_t stream) {
    const float* x   = (const float*)d_in[0];
    const float* A   = (const float*)d_in[1];
    const float* Wf  = (const float*)d_in[2];
    const float* bf  = (const float*)d_in[3];
    const float* Wm1 = (const float*)d_in[4];
    const float* bm1 = (const float*)d_in[5];
    const float* Wm2 = (const float*)d_in[6];
    const float* bm2 = (const float*)d_in[7];
    const float* Wrm = (const float*)d_in[8];
    const float* brm = (const float*)d_in[9];
    float* out = (float*)d_out;

    char* ws = (char*)d_ws;
    unsigned short* xf = (unsigned short*)ws;                 // 32 MB
    size_t off = (size_t)N_ * COUT_ * T_ * V_ * 2;
    float* bT     = (float*)(ws + off); off += (size_t)N_ * V_ * K_ * 4;    // 2 MB
    float* a_pack = (float*)(ws + off); off += (size_t)N_ * V_ * K_ * 4;    // 2 MB
    float* AT     = (float*)(ws + off); off += (size_t)COUT_ * V_ * V_ * 4; // 4 MB
    unsigned short* wfrag  = (unsigned short*)(ws + off); off += 4 * 4 * 64 * 8 * 2; // 16 KB
    unsigned short* wffrag = (unsigned short*)(ws + off); off += 5 * 2 * 64 * 8 * 2; // 10 KB
    unsigned short* xmT = (unsigned short*)(ws + off);        // 64 MB

    k0_transpose_A<<<dim3(COUT_, 16), 256, 0, stream>>>(A, AT);
    k0bc_frag<<<7, 256, 0, stream>>>(Wrm, Wf, Wm1, Wm2, wfrag, wffrag);
    k1_mfma<<<dim3(N_, (T_ * V_) / 256), 256, 0, stream>>>(
        x, wffrag, bf, bm1, bm2, xf, a_pack, bT);
    k2_mfma<<<dim3(N_, V_ * 2), 256, 0, stream>>>(a_pack, bT, wfrag, brm, AT, xmT);
    k3_mfma<<<dim3(N_, T_), 256, 0, stream>>>(xf, xmT, out);
}

// Round 12
// 214.782 us; speedup vs baseline: 1.0862x; 1.0862x over previous
//
#include <hip/hip_runtime.h>
#include <hip/hip_bf16.h>

#define N_ 32
#define CIN_ 64
#define COUT_ 64
#define T_ 64
#define V_ 128
#define K_ 128  // RED_*T_

#define C2LOG2E 2.88539008177792681f  // 2*log2(e): tanh(x)=1-2/(2^(C*x)+1)

typedef __attribute__((ext_vector_type(8))) short short8v;  // 8 bf16 = 4 VGPR
typedef __attribute__((ext_vector_type(4))) short short4v;  // 4 bf16 = 2 VGPR
typedef __attribute__((ext_vector_type(4))) float f32x4;    // MFMA acc

// d = 2*log2e*(b-a) pre-scaled in k1 -> tanh = 1 - 2/(exp2(d)+1)
__device__ __forceinline__ float tanh_ps(float d) {
    float e = __builtin_amdgcn_exp2f(d);
    return 1.0f - 2.0f * __builtin_amdgcn_rcpf(e + 1.0f);
}
__device__ __forceinline__ unsigned short f2bf(float f) {
    __hip_bfloat16 h = __float2bfloat16(f);
    return *reinterpret_cast<unsigned short*>(&h);
}

// fragment k-order: element jj of chunk (kc,g) holds k = kc*32 + 4g + (jj<4 ? jj : 12+jj)
// flat fragment index k' = (kc*4+g)*8 + jj
__device__ __forceinline__ int kprime(int k) {
    int kc = k >> 5, kk = k & 31;
    int hi = kk >> 4;
    int base = kk & 15;
    int g = base >> 2, j = base & 3;
    return kc * 32 + g * 8 + hi * 4 + j;
}

// a_pack float index: lane-contiguous (8 floats) AND wave-contiguous (2KB/frag)
__device__ __forceinline__ size_t apos(int n, int v, int kp) {
    return (size_t)n * 16384 + (size_t)(v >> 4) * 2048
         + (size_t)(kp >> 3) * 128 + (size_t)(v & 15) * 8 + (kp & 7);
}

// ---------------------------------------------------------------------------
// k0_prep: MERGED k0a (A-transpose) + k0bc (weight-fragment tables).
// Blocks 0..1023: AT[o][w][v] = A[o][v][w] (32x32 LDS tiles).
// Blocks 1024..1030: wfrag (16 KB, k2) and wffrag (10 KB, k1) tables.
// Merge removes one kernel boundary — probe for the ~13-16us/boundary
// launch-gap theory (R11 post-mortem: ~80us of wall time unaccounted).
// ---------------------------------------------------------------------------
__global__ __launch_bounds__(256) void k0_prep(
    const float* __restrict__ A, float* __restrict__ AT,
    const float* __restrict__ Wrm, const float* __restrict__ Wf,
    const float* __restrict__ Wm1, const float* __restrict__ Wm2,
    unsigned short* __restrict__ wfrag, unsigned short* __restrict__ wffrag)
{
    const int b = blockIdx.x;
    if (b < 1024) {
        __shared__ float t[32][33];
        const int o  = b >> 4, ty = b & 15;
        const int v0 = (ty >> 2) * 32, w0 = (ty & 3) * 32;
        const float* Ao = A  + (size_t)o * (V_ * V_);
        float*      ATo = AT + (size_t)o * (V_ * V_);
        for (int i = threadIdx.x; i < 1024; i += 256) {
            int r = i >> 5, c = i & 31;
            t[r][c] = Ao[(v0 + r) * V_ + (w0 + c)];
        }
        __syncthreads();
        for (int i = threadIdx.x; i < 1024; i += 256) {
            int r = i >> 5, c = i & 31;
            ATo[(w0 + r) * V_ + (v0 + c)] = t[c][r];
        }
        return;
    }
    const int flat = (b - 1024) * 256 + threadIdx.x;
    if (flat < 1024) {
        const int ent = flat;
        const int lane = ent & 63, kc = (ent >> 6) & 3, ot = ent >> 8;
        const int l15 = lane & 15, g = lane >> 4;
        const float* wr = Wrm + (size_t)(ot * 16 + l15) * K_ + kc * 32 + 4 * g;
        short8v f;
        #pragma unroll
        for (int j = 0; j < 4; ++j) f[j]     = (short)f2bf(wr[j]);
        #pragma unroll
        for (int j = 0; j < 4; ++j) f[4 + j] = (short)f2bf(wr[16 + j]);
        reinterpret_cast<short8v*>(wfrag)[ent] = f;
    } else if (flat < 1024 + 640) {
        const int ent = flat - 1024;
        const int lane = ent & 63, kc = (ent >> 6) & 1, ot = ent >> 7;
        const int l15 = lane & 15, g = lane >> 4;
        short8v f = (short8v){0, 0, 0, 0, 0, 0, 0, 0};
        const float* wr = nullptr;
        if (ot < 4)          wr = Wf  + (size_t)(ot * 16 + l15) * CIN_;
        else if (l15 < 2)    wr = Wm1 + (size_t)l15 * CIN_;
        else if (l15 < 4)    wr = Wm2 + (size_t)(l15 - 2) * CIN_;
        if (wr) {
            wr += kc * 32 + 4 * g;
            #pragma unroll
            for (int j = 0; j < 4; ++j) f[j]     = (short)f2bf(wr[j]);
            #pragma unroll
            for (int j = 0; j < 4; ++j) f[4 + j] = (short)f2bf(wr[16 + j]);
        }
        reinterpret_cast<short8v*>(wffrag)[ent] = f;
    }
}

// ---------------------------------------------------------------------------
// k1: all three 1x1 convs as one MFMA GEMM. Per block (n, 256-col tv chunk).
// a_pack/bT PRE-SCALED by 2*log2e (both feed only k2's tanh argument).
// ---------------------------------------------------------------------------
__global__ __launch_bounds__(256) void k1_mfma(
    const float* __restrict__ x,
    const unsigned short* __restrict__ wffrag,
    const float* __restrict__ bfv,
    const float* __restrict__ bm1, const float* __restrict__ bm2,
    unsigned short* __restrict__ xf, float* __restrict__ a_pack,
    float* __restrict__ bT)
{
    const int n = blockIdx.x, tv0 = blockIdx.y * 256;
    const int tid = threadIdx.x, lane = tid & 63, wid = tid >> 6;
    const int l15 = lane & 15, g = lane >> 4;
    const float* xn = x + (size_t)n * (CIN_ * T_ * V_);
    const int colbase = tv0 + wid * 64 + l15;

    f32x4 acc[5][4];
    #pragma unroll
    for (int ot = 0; ot < 5; ++ot)
        #pragma unroll
        for (int nt = 0; nt < 4; ++nt)
            acc[ot][nt] = (f32x4){0.f, 0.f, 0.f, 0.f};

    const short8v* wf = reinterpret_cast<const short8v*>(wffrag);
    #pragma unroll
    for (int kc = 0; kc < 2; ++kc) {
        short8v bfrag[4];
        #pragma unroll
        for (int nt = 0; nt < 4; ++nt) {
            const float* xp = xn + (size_t)(kc * 32 + 4 * g) * (T_ * V_)
                            + colbase + nt * 16;
            short8v t;
            #pragma unroll
            for (int j = 0; j < 4; ++j)
                t[j]     = (short)f2bf(xp[(size_t)j * (T_ * V_)]);
            #pragma unroll
            for (int j = 0; j < 4; ++j)
                t[4 + j] = (short)f2bf(xp[(size_t)(16 + j) * (T_ * V_)]);
            bfrag[nt] = t;
        }
        #pragma unroll
        for (int ot = 0; ot < 5; ++ot) {
            short8v wv = wf[(ot * 2 + kc) * 64 + lane];
            #pragma unroll
            for (int nt = 0; nt < 4; ++nt)
                acc[ot][nt] = __builtin_amdgcn_mfma_f32_16x16x32_bf16(
                    wv, bfrag[nt], acc[ot][nt], 0, 0, 0);
        }
    }

    // xf epilogue: row o = ot*16+4g+r, col = colbase+nt*16
    #pragma unroll
    for (int ot = 0; ot < 4; ++ot) {
        float4 bias = *reinterpret_cast<const float4*>(bfv + ot * 16 + 4 * g);
        const float bi[4] = {bias.x, bias.y, bias.z, bias.w};
        #pragma unroll
        for (int nt = 0; nt < 4; ++nt) {
            const int col = colbase + nt * 16;
            #pragma unroll
            for (int r = 0; r < 4; ++r) {
                const int o = ot * 16 + 4 * g + r;
                xf[((size_t)n * COUT_ + o) * (T_ * V_) + col] =
                    f2bf(acc[ot][nt][r] + bi[r]);
            }
        }
    }

    // a/b epilogue: only g==0 lanes hold rows 0..3 of the Wm tile
    if (g == 0) {
        const float b10 = bm1[0], b11 = bm1[1], b20 = bm2[0], b21 = bm2[1];
        #pragma unroll
        for (int nt = 0; nt < 4; ++nt) {
            const int tv = colbase + nt * 16;
            const int t = tv >> 7, v = tv & 127;
            a_pack[apos(n, v, kprime(t))]      = C2LOG2E * (acc[4][nt][0] + b10);
            a_pack[apos(n, v, kprime(64 + t))] = C2LOG2E * (acc[4][nt][1] + b11);
            float* btp = bT + ((size_t)n * V_ + v) * K_;
            btp[t]      = C2LOG2E * (acc[4][nt][2] + b20);
            btp[64 + t] = C2LOG2E * (acc[4][nt][3] + b21);
        }
    }
}

// ---------------------------------------------------------------------------
// k2: MFMA. Per block (n, w): C'[o][v] = sum_k Wrm[o][k]*tanh(b[k][w]-a[k][v])
// xmT[n][o][w][v] = brm[o] + A[o][v][w] - C'[o][v].
// R12: REVERTED to R9's best-measured structure (43.4us): e[2][4], acc[4][2],
// 128 v/block, single-pass epilogue. R10's LDS-halving and R11's v-split both
// regressed (occupancy was not the limiter; per-block fixed costs doubled).
// Only the exp2 pre-scale is kept (strictly one fewer mul per tanh).
// ---------------------------------------------------------------------------
__global__ __launch_bounds__(256) void k2_mfma(
    const float* __restrict__ a_pack, const float* __restrict__ bT,
    const unsigned short* __restrict__ wfrag, const float* __restrict__ brm,
    const float* __restrict__ AT, unsigned short* __restrict__ xmT)
{
    __shared__ float tile[COUT_][V_ + 2];  // stride 130: 8B-aligned rows
    const int n = blockIdx.x, w = blockIdx.y;
    const int tid  = threadIdx.x;
    const int lane = tid & 63, wid = tid >> 6;
    const int l15  = lane & 15, g = lane >> 4;

    const float* bt = bT + ((size_t)n * V_ + w) * K_;

    short8v e[2][4];
    #pragma unroll
    for (int vt = 0; vt < 2; ++vt) {
        const float* ap = a_pack + (size_t)n * 16384
                        + (size_t)(wid * 2 + vt) * 2048 + (size_t)l15 * 8;
        #pragma unroll
        for (int kc = 0; kc < 4; ++kc) {
            float4 a0 = *reinterpret_cast<const float4*>(ap + (kc * 4 + g) * 128);
            float4 a1 = *reinterpret_cast<const float4*>(ap + (kc * 4 + g) * 128 + 4);
            float4 bl = *reinterpret_cast<const float4*>(bt + kc * 32 + 4 * g);
            float4 bh = *reinterpret_cast<const float4*>(bt + kc * 32 + 4 * g + 16);
            short8v t;
            t[0] = (short)f2bf(tanh_ps(bl.x - a0.x));
            t[1] = (short)f2bf(tanh_ps(bl.y - a0.y));
            t[2] = (short)f2bf(tanh_ps(bl.z - a0.z));
            t[3] = (short)f2bf(tanh_ps(bl.w - a0.w));
            t[4] = (short)f2bf(tanh_ps(bh.x - a1.x));
            t[5] = (short)f2bf(tanh_ps(bh.y - a1.y));
            t[6] = (short)f2bf(tanh_ps(bh.z - a1.z));
            t[7] = (short)f2bf(tanh_ps(bh.w - a1.w));
            e[vt][kc] = t;
        }
    }

    const short8v* wf = reinterpret_cast<const short8v*>(wfrag);
    f32x4 acc[4][2];
    #pragma unroll
    for (int ot = 0; ot < 4; ++ot) {
        acc[ot][0] = (f32x4){0.f, 0.f, 0.f, 0.f};
        acc[ot][1] = (f32x4){0.f, 0.f, 0.f, 0.f};
    }
    #pragma unroll
    for (int ot = 0; ot < 4; ++ot)
        #pragma unroll
        for (int kc = 0; kc < 4; ++kc) {
            short8v wv = wf[(ot * 4 + kc) * 64 + lane];
            acc[ot][0] = __builtin_amdgcn_mfma_f32_16x16x32_bf16(wv, e[0][kc], acc[ot][0], 0, 0, 0);
            acc[ot][1] = __builtin_amdgcn_mfma_f32_16x16x32_bf16(wv, e[1][kc], acc[ot][1], 0, 0, 0);
        }

    #pragma unroll
    for (int ot = 0; ot < 4; ++ot)
        #pragma unroll
        for (int vt = 0; vt < 2; ++vt)
            #pragma unroll
            for (int r = 0; r < 4; ++r)
                tile[ot * 16 + 4 * g + r][wid * 32 + vt * 16 + l15] = acc[ot][vt][r];
    __syncthreads();

    for (int i = tid; i < COUT_ * 64; i += 256) {
        int o = i >> 6, vp = i & 63;
        float2 tv2 = *reinterpret_cast<const float2*>(&tile[o][2 * vp]);
        float2 at = *reinterpret_cast<const float2*>(
            AT + ((size_t)o * V_ + w) * V_ + 2 * vp);
        float br = brm[o];
        unsigned u = (unsigned)f2bf(br + at.x - tv2.x)
                   | ((unsigned)f2bf(br + at.y - tv2.y) << 16);
        reinterpret_cast<unsigned*>(xmT)[(((size_t)n * COUT_ + o) * V_ + w) * 64 + vp] = u;
    }
}

// ---------------------------------------------------------------------------
// k3: MFMA. Per block (n, t): out[c][w] = sum_v xf[c][v] * xmT[t][w][v].
// ---------------------------------------------------------------------------
__global__ __launch_bounds__(256) void k3_mfma(
    const unsigned short* __restrict__ xf,
    const unsigned short* __restrict__ xmT,
    float* __restrict__ out)
{
    __shared__ unsigned short xfl[COUT_ * V_];
    __shared__ unsigned short xml[V_ * V_];
    const int n = blockIdx.x, t = blockIdx.y;
    const int tid  = threadIdx.x;
    const int lane = tid & 63, wid = tid >> 6;
    const int l15  = lane & 15, g = lane >> 4;

    for (int i = tid; i < 1024; i += 256) {
        int c = i >> 4, ch = i & 15;
        float4 d = *reinterpret_cast<const float4*>(
            xf + (((size_t)n * COUT_ + c) * T_ + t) * V_ + ch * 8);
        int dst = c * 256 + ((ch * 16) ^ ((c & 7) << 4));
        *reinterpret_cast<float4*>(reinterpret_cast<char*>(xfl) + dst) = d;
    }
    for (int i = tid; i < 2048; i += 256) {
        int wq = i >> 4, ch = i & 15;
        float4 d = *reinterpret_cast<const float4*>(
            xmT + (((size_t)n * COUT_ + t) * V_ + wq) * V_ + ch * 8);
        int dst = wq * 256 + ((ch * 16) ^ ((wq & 7) << 4));
        *reinterpret_cast<float4*>(reinterpret_cast<char*>(xml) + dst) = d;
    }
    __syncthreads();

    f32x4 acc[4][2];
    #pragma unroll
    for (int ct = 0; ct < 4; ++ct) {
        acc[ct][0] = (f32x4){0.f, 0.f, 0.f, 0.f};
        acc[ct][1] = (f32x4){0.f, 0.f, 0.f, 0.f};
    }

    #pragma unroll
    for (int kc = 0; kc < 4; ++kc) {
        const int vb0 = (kc * 32 + 4 * g) * 2;
        const int vb1 = vb0 + 32;
        short8v af[4];
        #pragma unroll
        for (int ct = 0; ct < 4; ++ct) {
            int c = ct * 16 + l15, sw = (c & 7) << 4;
            short4v lo = *reinterpret_cast<const short4v*>(
                reinterpret_cast<const char*>(xfl) + c * 256 + (vb0 ^ sw));
            short4v hi = *reinterpret_cast<const short4v*>(
                reinterpret_cast<const char*>(xfl) + c * 256 + (vb1 ^ sw));
            af[ct] = __builtin_shufflevector(lo, hi, 0, 1, 2, 3, 4, 5, 6, 7);
        }
        short8v bg[2];
        #pragma unroll
        for (int wt = 0; wt < 2; ++wt) {
            int wq = wid * 32 + wt * 16 + l15, sw = (wq & 7) << 4;
            short4v lo = *reinterpret_cast<const short4v*>(
                reinterpret_cast<const char*>(xml) + wq * 256 + (vb0 ^ sw));
            short4v hi = *reinterpret_cast<const short4v*>(
                reinterpret_cast<const char*>(xml) + wq * 256 + (vb1 ^ sw));
            bg[wt] = __builtin_shufflevector(lo, hi, 0, 1, 2, 3, 4, 5, 6, 7);
        }
        #pragma unroll
        for (int ct = 0; ct < 4; ++ct)
            #pragma unroll
            for (int wt = 0; wt < 2; ++wt)
                acc[ct][wt] = __builtin_amdgcn_mfma_f32_16x16x32_bf16(
                    af[ct], bg[wt], acc[ct][wt], 0, 0, 0);
    }

    #pragma unroll
    for (int ct = 0; ct < 4; ++ct)
        #pragma unroll
        for (int wt = 0; wt < 2; ++wt)
            #pragma unroll
            for (int r = 0; r < 4; ++r) {
                int c = ct * 16 + 4 * g + r;
                int wcol = wid * 32 + wt * 16 + l15;
                out[(((size_t)n * COUT_ + c) * T_ + t) * V_ + wcol] = acc[ct][wt][r];
            }
}

extern "C" void kernel_launch(void* const* d_in, const int* in_sizes, int n_in,
                              void* d_out, int out_size, void* d_ws, size_t ws_size,
                              hipStream_t stream) {
    const float* x   = (const float*)d_in[0];
    const float* A   = (const float*)d_in[1];
    const float* Wf  = (const float*)d_in[2];
    const float* bf  = (const float*)d_in[3];
    const float* Wm1 = (const float*)d_in[4];
    const float* bm1 = (const float*)d_in[5];
    const float* Wm2 = (const float*)d_in[6];
    const float* bm2 = (const float*)d_in[7];
    const float* Wrm = (const float*)d_in[8];
    const float* brm = (const float*)d_in[9];
    float* out = (float*)d_out;

    char* ws = (char*)d_ws;
    unsigned short* xf = (unsigned short*)ws;                 // 32 MB
    size_t off = (size_t)N_ * COUT_ * T_ * V_ * 2;
    float* bT     = (float*)(ws + off); off += (size_t)N_ * V_ * K_ * 4;    // 2 MB
    float* a_pack = (float*)(ws + off); off += (size_t)N_ * V_ * K_ * 4;    // 2 MB
    float* AT     = (float*)(ws + off); off += (size_t)COUT_ * V_ * V_ * 4; // 4 MB
    unsigned short* wfrag  = (unsigned short*)(ws + off); off += 4 * 4 * 64 * 8 * 2; // 16 KB
    unsigned short* wffrag = (unsigned short*)(ws + off); off += 5 * 2 * 64 * 8 * 2; // 10 KB
    unsigned short* xmT = (unsigned short*)(ws + off);        // 64 MB

    k0_prep<<<1031, 256, 0, stream>>>(A, AT, Wrm, Wf, Wm1, Wm2, wfrag, wffrag);
    k1_mfma<<<dim3(N_, (T_ * V_) / 256), 256, 0, stream>>>(
        x, wffrag, bf, bm1, bm2, xf, a_pack, bT);
    k2_mfma<<<dim3(N_, V_), 256, 0, stream>>>(a_pack, bT, wfrag, brm, AT, xmT);
    k3_mfma<<<dim3(N_, T_), 256, 0, stream>>>(xf, xmT, out);
}